// Round 7
// baseline (537.500 us; speedup 1.0000x reference)
//
#include <hip/hip_runtime.h>

constexpr int NL    = 48;
constexpr int SEQ   = 1024;
constexpr int BATCH = 512;

__device__ __forceinline__ float lane_bcast(float v, int lane) {
    return __int_as_float(__builtin_amdgcn_readlane(__float_as_int(v), lane));
}

// One step of TWO interleaved forward chains (batches A and B in one wave).
// Round 4/6 lesson: a single chain stalls ~387 cy/step on dependency wait
// states that one resident wave can't fill. Chains A and B are independent,
// so interleaving their readlane->fma streams fills each other's stalls.
// Grouped by 8 to keep live broadcast SGPRs ~16 (<< 102 SGPR wave budget).
// RN_: per-chain renorm max on the scalar pipe over the streamed sv values
// (positive floats order as unsigned); scale folds into this step's output
// identically on both mask paths (exact identity, proven rounds 4-6).
#define CRF_STEP2(T_, SLOT_, RN_) do {                                        \
    float eeA_ = __expf(embufA[SLOT_]);                                       \
    float eeB_ = __expf(embufB[SLOT_]);                                       \
    int   mtA_ = mbufA[SLOT_], mtB_ = mbufB[SLOT_];                           \
    int   tn_ = (T_) + 8; if (tn_ > SEQ - 1) tn_ = SEQ - 1;                   \
    embufA[SLOT_] = emA[tn_ * NL + jc];  mbufA[SLOT_] = mkA[tn_];             \
    embufB[SLOT_] = emB[tn_ * NL + jc];  mbufB[SLOT_] = mkB[tn_];             \
    float a0_=0.f,a1_=0.f,a2_=0.f,a3_=0.f;                                    \
    float b0_=0.f,b1_=0.f,b2_=0.f,b3_=0.f;                                    \
    unsigned umA_ = 0u, umB_ = 0u;                                            \
    _Pragma("unroll")                                                         \
    for (int g_ = 0; g_ < NL; g_ += 8) {                                      \
        float sA_[8], sB_[8];                                                 \
        _Pragma("unroll")                                                     \
        for (int k_ = 0; k_ < 8; ++k_) {                                      \
            sA_[k_] = lane_bcast(vA, g_ + k_);                                \
            sB_[k_] = lane_bcast(vB, g_ + k_);                                \
        }                                                                     \
        if (RN_) {                                                            \
            _Pragma("unroll")                                                 \
            for (int k_ = 0; k_ < 8; ++k_) {                                  \
                unsigned uA_ = __float_as_uint(sA_[k_]);                      \
                umA_ = (umA_ > uA_) ? umA_ : uA_;                             \
                unsigned uB_ = __float_as_uint(sB_[k_]);                      \
                umB_ = (umB_ > uB_) ? umB_ : uB_;                             \
            }                                                                 \
        }                                                                     \
        _Pragma("unroll")                                                     \
        for (int k_ = 0; k_ < 8; k_ += 4) {                                   \
            a0_ = fmaf(sA_[k_+0], Ec[g_+k_+0], a0_);                          \
            b0_ = fmaf(sB_[k_+0], Ec[g_+k_+0], b0_);                          \
            a1_ = fmaf(sA_[k_+1], Ec[g_+k_+1], a1_);                          \
            b1_ = fmaf(sB_[k_+1], Ec[g_+k_+1], b1_);                          \
            a2_ = fmaf(sA_[k_+2], Ec[g_+k_+2], a2_);                          \
            b2_ = fmaf(sB_[k_+2], Ec[g_+k_+2], b2_);                          \
            a3_ = fmaf(sA_[k_+3], Ec[g_+k_+3], a3_);                          \
            b3_ = fmaf(sB_[k_+3], Ec[g_+k_+3], b3_);                          \
        }                                                                     \
    }                                                                         \
    float rmA_ = 1.0f, rmB_ = 1.0f;                                           \
    if (RN_) {                                                                \
        float mA_ = __uint_as_float(umA_);                                    \
        float mB_ = __uint_as_float(umB_);                                    \
        rmA_ = __builtin_amdgcn_rcpf(mA_);  SA += __logf(mA_);                \
        rmB_ = __builtin_amdgcn_rcpf(mB_);  SB += __logf(mB_);                \
    }                                                                         \
    float accA_ = (a0_ + a1_) + (a2_ + a3_);                                  \
    float accB_ = (b0_ + b1_) + (b2_ + b3_);                                  \
    vA = (mtA_ ? accA_ * eeA_ : vA) * rmA_;                                   \
    vB = (mtB_ ? accB_ * eeB_ : vB) * rmB_;                                   \
} while (0)

// Grid = 256 blocks x 128 threads. Wave 0: forward chains for batches
// blockIdx.x and blockIdx.x+256 (interleaved). Wave 1: gold for both.
// amdgpu_waves_per_eu(1,1): full VGPR budget (proven round 4).
__global__ __launch_bounds__(128)
__attribute__((amdgpu_waves_per_eu(1, 1)))
void crf_fused(
    const float* __restrict__ emissions, const int* __restrict__ labels,
    const int* __restrict__ mask, const float* __restrict__ trans,
    const float* __restrict__ startt, const float* __restrict__ endt,
    float* __restrict__ gold_out, float* __restrict__ fwd_out)
{
    const int bA  = blockIdx.x;
    const int bB  = blockIdx.x + (BATCH / 2);
    const int tid = threadIdx.x;

    if (tid < 64) {
        // ---------------- wave 0: two interleaved forward chains ----------
        const int  j   = tid;                  // lanes 48..63 mirror lane 47
        const bool act = (j < NL);
        const int  jc  = act ? j : NL - 1;

        const float* emA = emissions + (size_t)bA * SEQ * NL;
        const float* emB = emissions + (size_t)bB * SEQ * NL;
        const int*   mkA = mask + bA * SEQ;
        const int*   mkB = mask + bB * SEQ;

        // E column jc (shared by both chains): Ec[i] = exp(T[i][jc]).
        float Ec[NL];
        #pragma unroll
        for (int i = 0; i < NL; ++i) Ec[i] = __expf(trans[i * NL + jc]);

        // init both chains: score0 = start + emit[0]; normalize by wave max.
        float st_ = act ? startt[jc] : 0.0f;
        float s0A = act ? (st_ + emA[jc]) : -3.0e38f;
        float s0B = act ? (st_ + emB[jc]) : -3.0e38f;
        float m0A = s0A, m0B = s0B;
        #pragma unroll
        for (int o = 32; o; o >>= 1) {
            m0A = fmaxf(m0A, __shfl_xor(m0A, o));
            m0B = fmaxf(m0B, __shfl_xor(m0B, o));
        }
        float vA = act ? __expf(s0A - m0A) : 0.0f;
        float vB = act ? __expf(s0B - m0B) : 0.0f;
        float SA = m0A, SB = m0B;

        // 8-deep prefetch rings for emissions + mask, per chain.
        float embufA[8], embufB[8]; int mbufA[8], mbufB[8];
        #pragma unroll
        for (int t = 1; t <= 8; ++t) {
            embufA[t & 7] = emA[t * NL + jc];  mbufA[t & 7] = mkA[t];
            embufB[t & 7] = emB[t * NL + jc];  mbufB[t & 7] = mkB[t];
        }

        // peeled steps 1..7; renorm at step 5 (max over v from step 4).
        CRF_STEP2(1, 1, 0); CRF_STEP2(2, 2, 0); CRF_STEP2(3, 3, 0); CRF_STEP2(4, 4, 0);
        CRF_STEP2(5, 5, 1); CRF_STEP2(6, 6, 0); CRF_STEP2(7, 7, 0);

        // aligned chunks of 8: tb = 8,16,...,1016 covers t = 8..1023.
        // renorm at tb+0 and tb+4 -> every <=4 steps (fp32-safe growth).
        for (int tb = 8; tb <= SEQ - 8; tb += 8) {
            CRF_STEP2(tb + 0, 0, 1);
            CRF_STEP2(tb + 1, 1, 0); CRF_STEP2(tb + 2, 2, 0); CRF_STEP2(tb + 3, 3, 0);
            CRF_STEP2(tb + 4, 4, 1);
            CRF_STEP2(tb + 5, 5, 0); CRF_STEP2(tb + 6, 6, 0); CRF_STEP2(tb + 7, 7, 0);
        }

        // fwd = S + log(sum_j v[j] * exp(end[j])) per chain.
        float ed_ = act ? __expf(endt[jc]) : 0.0f;
        float wA = act ? vA * ed_ : 0.0f;
        float wB = act ? vB * ed_ : 0.0f;
        #pragma unroll
        for (int o = 32; o; o >>= 1) {
            wA += __shfl_xor(wA, o);
            wB += __shfl_xor(wB, o);
        }
        if (j == 0) {
            fwd_out[bA] = SA + __logf(wA);
            fwd_out[bB] = SB + __logf(wB);
        }
    } else {
        // ---------------- wave 1: gold score for both batches -------------
        const int l = tid - 64;
        #pragma unroll
        for (int c = 0; c < 2; ++c) {
            const int bb = (c == 0) ? bA : bB;
            const int*   lb = labels + bb * SEQ;
            const int*   mk = mask + bb * SEQ;
            const float* em = emissions + (size_t)bb * SEQ * NL;

            float part = 0.0f; int mcnt = 0;
            for (int t = l; t < SEQ; t += 64) {
                int lt = lb[t];
                int mt = mk[t];
                mcnt += mt;
                if (t == 0) {
                    part += startt[lt] + em[lt];
                } else {
                    float e  = em[t * NL + lt];
                    float tr = trans[lt * NL + lb[t - 1]];  // gold: T[cur][prev]
                    if (mt) part += e + tr;
                }
            }
            #pragma unroll
            for (int o = 32; o; o >>= 1) {
                part += __shfl_xor(part, o);
                mcnt += __shfl_xor(mcnt, o);
            }
            if (l == 0) {
                int len = mcnt - 1;
                gold_out[bb] = part + endt[lb[len]];
            }
        }
    }
}

__global__ __launch_bounds__(64) void crf_reduce(
    const float* __restrict__ gold, const float* __restrict__ fwd,
    float* __restrict__ out)
{
    const int l = threadIdx.x;
    float s = 0.0f;
    for (int bIdx = l; bIdx < BATCH; bIdx += 64) s += fwd[bIdx] - gold[bIdx];
    #pragma unroll
    for (int o = 32; o; o >>= 1) s += __shfl_xor(s, o);
    if (l == 0) out[0] = s * (1.0f / (float)BATCH);
}

extern "C" void kernel_launch(void* const* d_in, const int* in_sizes, int n_in,
                              void* d_out, int out_size, void* d_ws, size_t ws_size,
                              hipStream_t stream) {
    const float* emissions = (const float*)d_in[0];
    const int*   labels    = (const int*)d_in[1];
    const int*   mask      = (const int*)d_in[2];
    const float* trans     = (const float*)d_in[3];
    const float* startt    = (const float*)d_in[4];
    const float* endt      = (const float*)d_in[5];
    float*       out       = (float*)d_out;
    float*       wsf       = (float*)d_ws;   // [0..512) gold, [512..1024) fwd

    crf_fused<<<BATCH / 2, 128, 0, stream>>>(emissions, labels, mask, trans,
                                             startt, endt, wsf, wsf + BATCH);
    crf_reduce<<<1, 64, 0, stream>>>(wsf, wsf + BATCH, out);
}

// Round 8
// 521.061 us; speedup vs baseline: 1.0315x; 1.0315x over previous
//
#include <hip/hip_runtime.h>

constexpr int NL    = 48;
constexpr int SEQ   = 1024;
constexpr int BATCH = 512;
constexpr int FWDB  = 32;     // forward blocks: 32 tiles x 16 batches
constexpr int LSTR  = 72;     // bf16 elems per batch row in LDS (48 v + 16 zeros + 8 pad; 144B, 16B-aligned rows)

typedef short bf16x8 __attribute__((ext_vector_type(8)));
typedef float f32x4  __attribute__((ext_vector_type(4)));

__device__ __forceinline__ unsigned short bf16r(float x) {
    unsigned u = __float_as_uint(x);
    u += 0x7FFFu + ((u >> 16) & 1u);            // round-to-nearest-even bf16
    return (unsigned short)(u >> 16);
}
__device__ __forceinline__ unsigned bf16pk(float a, float b) {
    unsigned ua = __float_as_uint(a); ua += 0x7FFFu + ((ua >> 16) & 1u);
    unsigned ub = __float_as_uint(b); ub += 0x7FFFu + ((ub >> 16) & 1u);
    return (ua >> 16) | (ub & 0xFFFF0000u);
}

// One step for 16 batches. D[c'][b] = sum_k E[k][16mt+c'] * v[k][b] via
// 6 MFMAs (3 output tiles x K=64, zero-padded). v round-trips LDS in bf16:
// lane holds D-layout (batch n=L&15, states 16mt+4q+{0..3}) -> 3 ds_write_b64;
// B-frags (batch n=L&15, states 8q+{0..7} / 32+8q+{0..7}) -> 2 ds_read_b128.
// Single wave => DS pipe in-order, no barrier. RN_: per-batch renorm of the
// PRE-step v (max over 12 regs + shfl_xor 16/32 across the q-group); scale
// folds into this step's output on both mask paths (exact identity).
#define STEP(T_, S_, RN_) do {                                                \
    const int    mt_ = mring[S_];                                             \
    const float4 e0_ = ering0[S_];                                            \
    const float4 e1_ = ering1[S_];                                            \
    const float4 e2_ = ering2[S_];                                            \
    { int tn_ = (T_) + 4; if (tn_ > SEQ - 1) tn_ = SEQ - 1;                   \
      ering0[S_] = *(const float4*)(emb + tn_ * NL + eoff0);                  \
      ering1[S_] = *(const float4*)(emb + tn_ * NL + eoff1);                  \
      ering2[S_] = *(const float4*)(emb + tn_ * NL + eoff2);                  \
      mring[S_]  = mkb[tn_]; }                                                \
    const bf16x8 bLo_ = *(const bf16x8*)&vb[rdLo];                            \
    const bf16x8 bHi_ = *(const bf16x8*)&vb[rdHi];                            \
    f32x4 d0_ = {0.f, 0.f, 0.f, 0.f};                                         \
    f32x4 d1_ = {0.f, 0.f, 0.f, 0.f};                                         \
    f32x4 d2_ = {0.f, 0.f, 0.f, 0.f};                                         \
    d0_ = __builtin_amdgcn_mfma_f32_16x16x32_bf16(aL[0], bLo_, d0_, 0, 0, 0); \
    d1_ = __builtin_amdgcn_mfma_f32_16x16x32_bf16(aL[1], bLo_, d1_, 0, 0, 0); \
    d2_ = __builtin_amdgcn_mfma_f32_16x16x32_bf16(aL[2], bLo_, d2_, 0, 0, 0); \
    d0_ = __builtin_amdgcn_mfma_f32_16x16x32_bf16(aH[0], bHi_, d0_, 0, 0, 0); \
    d1_ = __builtin_amdgcn_mfma_f32_16x16x32_bf16(aH[1], bHi_, d1_, 0, 0, 0); \
    d2_ = __builtin_amdgcn_mfma_f32_16x16x32_bf16(aH[2], bHi_, d2_, 0, 0, 0); \
    float rm_ = 1.0f;                                                         \
    if (RN_) {                                                                \
        float mx_ = fmaxf(fmaxf(fmaxf(vc0[0], vc0[1]), fmaxf(vc0[2], vc0[3])),\
                          fmaxf(fmaxf(vc1[0], vc1[1]), fmaxf(vc1[2], vc1[3])));\
        mx_ = fmaxf(mx_, fmaxf(fmaxf(vc2[0], vc2[1]), fmaxf(vc2[2], vc2[3]))); \
        mx_ = fmaxf(mx_, __shfl_xor(mx_, 16));                                \
        mx_ = fmaxf(mx_, __shfl_xor(mx_, 32));                                \
        rm_ = __builtin_amdgcn_rcpf(mx_);                                     \
        S  += __logf(mx_);                                                    \
    }                                                                         \
    vc0[0] = (mt_ ? d0_[0] * __expf(e0_.x) : vc0[0]) * rm_;                   \
    vc0[1] = (mt_ ? d0_[1] * __expf(e0_.y) : vc0[1]) * rm_;                   \
    vc0[2] = (mt_ ? d0_[2] * __expf(e0_.z) : vc0[2]) * rm_;                   \
    vc0[3] = (mt_ ? d0_[3] * __expf(e0_.w) : vc0[3]) * rm_;                   \
    vc1[0] = (mt_ ? d1_[0] * __expf(e1_.x) : vc1[0]) * rm_;                   \
    vc1[1] = (mt_ ? d1_[1] * __expf(e1_.y) : vc1[1]) * rm_;                   \
    vc1[2] = (mt_ ? d1_[2] * __expf(e1_.z) : vc1[2]) * rm_;                   \
    vc1[3] = (mt_ ? d1_[3] * __expf(e1_.w) : vc1[3]) * rm_;                   \
    vc2[0] = (mt_ ? d2_[0] * __expf(e2_.x) : vc2[0]) * rm_;                   \
    vc2[1] = (mt_ ? d2_[1] * __expf(e2_.y) : vc2[1]) * rm_;                   \
    vc2[2] = (mt_ ? d2_[2] * __expf(e2_.z) : vc2[2]) * rm_;                   \
    vc2[3] = (mt_ ? d2_[3] * __expf(e2_.w) : vc2[3]) * rm_;                   \
    *(uint2*)&vb[wr0] = make_uint2(bf16pk(vc0[0], vc0[1]), bf16pk(vc0[2], vc0[3])); \
    *(uint2*)&vb[wr1] = make_uint2(bf16pk(vc1[0], vc1[1]), bf16pk(vc1[2], vc1[3])); \
    *(uint2*)&vb[wr2] = make_uint2(bf16pk(vc2[0], vc2[1]), bf16pk(vc2[2], vc2[3])); \
} while (0)

// Blocks 0..31: MFMA forward for a 16-batch tile (1 wave). Blocks 32..95:
// gold score, 4 waves x 2 batches each (runs on other CUs concurrently).
__global__ __launch_bounds__(256)
__attribute__((amdgpu_waves_per_eu(1, 1)))
void crf_fused(
    const float* __restrict__ emissions, const int* __restrict__ labels,
    const int* __restrict__ mask, const float* __restrict__ trans,
    const float* __restrict__ startt, const float* __restrict__ endt,
    float* __restrict__ gold_out, float* __restrict__ fwd_out)
{
    __shared__ __align__(16) unsigned short vb[16 * LSTR];
    const int tid = threadIdx.x;

    if (blockIdx.x < FWDB) {
        if (tid >= 64) return;
        // ---------------- forward: 16 batches via MFMA ----------------
        const int L  = tid;
        const int n  = L & 15;                 // batch col (B/D), state m (A)
        const int q  = L >> 4;                 // quad
        const int bt = blockIdx.x;
        const int bn = 16 * bt + n;

        const float* emb = emissions + (size_t)bn * SEQ * NL;
        const int*   mkb = mask + bn * SEQ;

        const int eoff0 = 4 * q, eoff1 = 16 + 4 * q, eoff2 = 32 + 4 * q;
        const int rdLo = LSTR * n + 8 * q;     // states 8q..8q+7   (bf16 idx)
        const int rdHi = rdLo + 32;            // states 32+8q..    (zeros for q>=2)
        const int wr0  = LSTR * n + 4 * q;     // states 4q+{0..3}
        const int wr1  = wr0 + 16;
        const int wr2  = wr0 + 32;

        // Static A-frags: A[m][k] = exp(T[k][16mt+m]), m=n, k=8q+j (lo) /
        // 32+8q+j (hi, zero for k>=48). Layout verified (m120): lane&15=m,
        // k=quad*8+j.
        bf16x8 aL[3], aH[3];
        #pragma unroll
        for (int mt = 0; mt < 3; ++mt) {
            #pragma unroll
            for (int j = 0; j < 8; ++j) {
                int kL = 8 * q + j;
                aL[mt][j] = (short)bf16r(__expf(trans[kL * NL + 16 * mt + n]));
                int kH = 32 + 8 * q + j;
                int idx = (kH < NL) ? (kH * NL + 16 * mt + n) : 0;
                float tv = trans[idx];
                aH[mt][j] = (kH < NL) ? (short)bf16r(__expf(tv)) : (short)0;
            }
        }

        // zero LDS (incl. the k=48..63 pad the hi B-frag reads)
        for (int i = L; i < 16 * LSTR; i += 64) vb[i] = 0;

        // init t=0: v0 = exp(start + emit0 - m0), per-batch m0.
        float s_[12];
        #pragma unroll
        for (int mt = 0; mt < 3; ++mt)
            #pragma unroll
            for (int r = 0; r < 4; ++r) {
                int c = 16 * mt + 4 * q + r;
                s_[mt * 4 + r] = startt[c] + emb[c];
            }
        float mx = s_[0];
        #pragma unroll
        for (int i = 1; i < 12; ++i) mx = fmaxf(mx, s_[i]);
        mx = fmaxf(mx, __shfl_xor(mx, 16));
        mx = fmaxf(mx, __shfl_xor(mx, 32));
        float S = mx;
        f32x4 vc0, vc1, vc2;
        #pragma unroll
        for (int r = 0; r < 4; ++r) {
            vc0[r] = __expf(s_[r]     - mx);
            vc1[r] = __expf(s_[4 + r] - mx);
            vc2[r] = __expf(s_[8 + r] - mx);
        }
        *(uint2*)&vb[wr0] = make_uint2(bf16pk(vc0[0], vc0[1]), bf16pk(vc0[2], vc0[3]));
        *(uint2*)&vb[wr1] = make_uint2(bf16pk(vc1[0], vc1[1]), bf16pk(vc1[2], vc1[3]));
        *(uint2*)&vb[wr2] = make_uint2(bf16pk(vc2[0], vc2[1]), bf16pk(vc2[2], vc2[3]));

        // 4-deep prefetch ring
        float4 ering0[4], ering1[4], ering2[4]; int mring[4];
        #pragma unroll
        for (int t = 1; t <= 4; ++t) {
            int s = t & 3;
            ering0[s] = *(const float4*)(emb + t * NL + eoff0);
            ering1[s] = *(const float4*)(emb + t * NL + eoff1);
            ering2[s] = *(const float4*)(emb + t * NL + eoff2);
            mring[s]  = mkb[t];
        }

        STEP(1, 1, 0); STEP(2, 2, 0); STEP(3, 3, 0);
        for (int tb = 4; tb <= SEQ - 4; tb += 4) {
            STEP(tb + 0, 0, 1);
            STEP(tb + 1, 1, 0); STEP(tb + 2, 2, 0); STEP(tb + 3, 3, 0);
        }

        // fwd = S + log(sum_c v[c] * exp(end[c])), reduce over q-group.
        float w = 0.0f;
        #pragma unroll
        for (int mt = 0; mt < 3; ++mt)
            #pragma unroll
            for (int r = 0; r < 4; ++r) {
                int c = 16 * mt + 4 * q + r;
                float vv = (mt == 0) ? vc0[r] : (mt == 1) ? vc1[r] : vc2[r];
                w += vv * __expf(endt[c]);
            }
        w += __shfl_xor(w, 16);
        w += __shfl_xor(w, 32);
        if (q == 0) fwd_out[bn] = S + __logf(w);
    } else {
        // ---------------- gold score: 4 waves x 2 batches ----------------
        const int gb = blockIdx.x - FWDB;
        const int wv = tid >> 6;
        const int l  = tid & 63;
        #pragma unroll
        for (int c = 0; c < 2; ++c) {
            const int bb = gb * 8 + wv * 2 + c;
            const int*   lb = labels + bb * SEQ;
            const int*   mk = mask + bb * SEQ;
            const float* em = emissions + (size_t)bb * SEQ * NL;

            float part = 0.0f; int mcnt = 0;
            for (int t = l; t < SEQ; t += 64) {
                int lt = lb[t];
                int mt = mk[t];
                mcnt += mt;
                if (t == 0) {
                    part += startt[lt] + em[lt];
                } else {
                    float e  = em[t * NL + lt];
                    float tr = trans[lt * NL + lb[t - 1]];  // gold: T[cur][prev]
                    if (mt) part += e + tr;
                }
            }
            #pragma unroll
            for (int o = 32; o; o >>= 1) {
                part += __shfl_xor(part, o);
                mcnt += __shfl_xor(mcnt, o);
            }
            if (l == 0) {
                int len = mcnt - 1;
                gold_out[bb] = part + endt[lb[len]];
            }
        }
    }
}

__global__ __launch_bounds__(64) void crf_reduce(
    const float* __restrict__ gold, const float* __restrict__ fwd,
    float* __restrict__ out)
{
    const int l = threadIdx.x;
    float s = 0.0f;
    for (int bIdx = l; bIdx < BATCH; bIdx += 64) s += fwd[bIdx] - gold[bIdx];
    #pragma unroll
    for (int o = 32; o; o >>= 1) s += __shfl_xor(s, o);
    if (l == 0) out[0] = s * (1.0f / (float)BATCH);
}

extern "C" void kernel_launch(void* const* d_in, const int* in_sizes, int n_in,
                              void* d_out, int out_size, void* d_ws, size_t ws_size,
                              hipStream_t stream) {
    const float* emissions = (const float*)d_in[0];
    const int*   labels    = (const int*)d_in[1];
    const int*   mask      = (const int*)d_in[2];
    const float* trans     = (const float*)d_in[3];
    const float* startt    = (const float*)d_in[4];
    const float* endt      = (const float*)d_in[5];
    float*       out       = (float*)d_out;
    float*       wsf       = (float*)d_ws;   // [0..512) gold, [512..1024) fwd

    crf_fused<<<FWDB + 64, 256, 0, stream>>>(emissions, labels, mask, trans,
                                             startt, endt, wsf, wsf + BATCH);
    crf_reduce<<<1, 64, 0, stream>>>(wsf, wsf + BATCH, out);
}